// Round 1
// baseline (534.850 us; speedup 1.0000x reference)
//
#include <hip/hip_runtime.h>
#include <stdint.h>

#define BATCH 8
#define CH 256
#define HW 4096
#define OC 768  // 3*CH

typedef __bf16 bf16;
typedef __attribute__((ext_vector_type(8))) __bf16 bf16x8;
typedef __attribute__((ext_vector_type(4))) __bf16 bf16x4;
typedef __attribute__((ext_vector_type(4))) float f32x4;

#define MFMA16(a, b, c) __builtin_amdgcn_mfma_f32_16x16x32_bf16(a, b, c, 0, 0, 0)

static __device__ __forceinline__ void gl2lds16(const void* g, void* l) {
  __builtin_amdgcn_global_load_lds((const __attribute__((address_space(1))) void*)g,
                                   (__attribute__((address_space(3))) void*)l, 16, 0, 0);
}

// ---------------- K1: GroupNorm stats -> per-(b,c) scale/shift ----------------
__global__ __launch_bounds__(1024) void gn_stats(const float* __restrict__ x,
    const float* __restrict__ nw, const float* __restrict__ nb,
    float* __restrict__ scale, float* __restrict__ shift) {
  int b = blockIdx.x >> 3, g = blockIdx.x & 7;
  const float4* p4 = (const float4*)(x + ((size_t)b * CH + g * 32) * HW);
  float s = 0.f, s2 = 0.f;
  for (int i = threadIdx.x; i < 32768; i += 1024) {
    float4 v = p4[i];
    s += v.x + v.y + v.z + v.w;
    s2 += v.x * v.x + v.y * v.y + v.z * v.z + v.w * v.w;
  }
  __shared__ float rs[16], rs2[16], mm[2];
  for (int off = 32; off; off >>= 1) { s += __shfl_down(s, off); s2 += __shfl_down(s2, off); }
  if ((threadIdx.x & 63) == 0) { rs[threadIdx.x >> 6] = s; rs2[threadIdx.x >> 6] = s2; }
  __syncthreads();
  if (threadIdx.x == 0) {
    float ts = 0.f, ts2 = 0.f;
    for (int w = 0; w < 16; w++) { ts += rs[w]; ts2 += rs2[w]; }
    float mean = ts * (1.0f / 131072.0f);
    float var = ts2 * (1.0f / 131072.0f) - mean * mean;
    mm[0] = mean; mm[1] = rsqrtf(var + 1e-5f);
  }
  __syncthreads();
  if (threadIdx.x < 32) {
    int c = g * 32 + threadIdx.x;
    float sc = nw[c] * mm[1];
    scale[b * CH + c] = sc;
    shift[b * CH + c] = nb[c] - mm[0] * sc;
  }
}

// ---------------- K2: fold GN into per-batch QKV weights (bf16) ----------------
__global__ __launch_bounds__(256) void fold_qkv(const float* __restrict__ qkv_w,
    const float* __restrict__ qkv_b, const float* __restrict__ scale,
    const float* __restrict__ shift, bf16* __restrict__ wq, float* __restrict__ bq) {
  int o = blockIdx.x, b = blockIdx.y, c = threadIdx.x;
  float w = qkv_w[o * CH + c];
  wq[((size_t)b * OC + o) * CH + c] = (bf16)(w * scale[b * CH + c]);
  float part = w * shift[b * CH + c];
  __shared__ float red[4];
  for (int off = 32; off; off >>= 1) part += __shfl_down(part, off);
  if ((threadIdx.x & 63) == 0) red[threadIdx.x >> 6] = part;
  __syncthreads();
  if (threadIdx.x == 0) bq[b * OC + o] = qkv_b[o] + red[0] + red[1] + red[2] + red[3];
}

// ---------------- K3: transpose x[b][c][p] fp32 -> xt[b][p][c] bf16 ----------------
__global__ __launch_bounds__(256) void transpose_x(const float* __restrict__ x,
                                                   bf16* __restrict__ xt) {
  __shared__ float tile[32][33];
  int b = blockIdx.z, p0 = blockIdx.x * 32, c0 = blockIdx.y * 32;
  const float* xb = x + (size_t)b * CH * HW;
#pragma unroll
  for (int i = 0; i < 4; i++) {
    int c = c0 + threadIdx.y + i * 8;
    tile[threadIdx.y + i * 8][threadIdx.x] = xb[(size_t)c * HW + p0 + threadIdx.x];
  }
  __syncthreads();
  bf16* xtb = xt + (size_t)b * HW * CH;
#pragma unroll
  for (int i = 0; i < 4; i++) {
    int p = p0 + threadIdx.y + i * 8;
    xtb[(size_t)p * CH + c0 + threadIdx.x] = (bf16)tile[threadIdx.x][threadIdx.y + i * 8];
  }
}

// ---------------- K4: proj_w -> bf16 ----------------
__global__ __launch_bounds__(256) void conv_projw(const float* __restrict__ w,
                                                  bf16* __restrict__ wb) {
  int i = blockIdx.x * 256 + threadIdx.x;
  wb[i] = (bf16)w[i];
}

// ---------------- K5: QKV GEMM (128x128 tile, BK=32, global_load_lds) ----------------
// A = wq[b] [768][256], BT = xt[b] [4096][256]. Writes qt/kt [p][c], v [c][p].
__global__ __launch_bounds__(256) void qkv_gemm(const bf16* __restrict__ wq,
    const float* __restrict__ bq, const bf16* __restrict__ xt,
    bf16* __restrict__ qt, bf16* __restrict__ kt, bf16* __restrict__ vv) {
  __shared__ __align__(16) bf16 As[128 * 32];
  __shared__ __align__(16) bf16 Bs[128 * 32];
  int b = blockIdx.z, row0 = blockIdx.y * 128, col0 = blockIdx.x * 128;
  const bf16* A = wq + (size_t)b * OC * CH + (size_t)row0 * CH;
  const bf16* Bt = xt + (size_t)b * HW * CH + (size_t)col0 * CH;
  int tid = threadIdx.x, lane = tid & 63, wave = tid >> 6;
  int wm = (wave & 1) * 64, wn = (wave >> 1) * 64;
  int l15 = lane & 15, quad = lane >> 4;
  f32x4 zero = {0.f, 0.f, 0.f, 0.f};
  f32x4 acc[4][4];
#pragma unroll
  for (int i = 0; i < 4; i++)
#pragma unroll
    for (int j = 0; j < 4; j++) acc[i][j] = zero;
  for (int k0 = 0; k0 < CH; k0 += 32) {
    __syncthreads();
#pragma unroll
    for (int i = 0; i < 2; i++) {
      int idx = i * 256 + tid, r = idx >> 2, ch = idx & 3;
      gl2lds16(A + (size_t)r * CH + k0 + ch * 8, As + idx * 8);
    }
#pragma unroll
    for (int i = 0; i < 2; i++) {
      int idx = i * 256 + tid, r = idx >> 2, ch = idx & 3;
      gl2lds16(Bt + (size_t)r * CH + k0 + ch * 8, Bs + idx * 8);
    }
    __syncthreads();
    bf16x8 af[4], bfr[4];
#pragma unroll
    for (int i = 0; i < 4; i++) {
      af[i] = *(const bf16x8*)(As + (wm + i * 16 + l15) * 32 + quad * 8);
      bfr[i] = *(const bf16x8*)(Bs + (wn + i * 16 + l15) * 32 + quad * 8);
    }
#pragma unroll
    for (int i = 0; i < 4; i++)
#pragma unroll
      for (int j = 0; j < 4; j++) acc[i][j] = MFMA16(af[i], bfr[j], acc[i][j]);
  }
#pragma unroll
  for (int i = 0; i < 4; i++) {
    int o = row0 + wm + i * 16 + quad * 4;  // + r
#pragma unroll
    for (int j = 0; j < 4; j++) {
      int p = col0 + wn + j * 16 + l15;
      if (o < CH) {  // q, fold 1/sqrt(C)=1/16
        bf16x4 pk;
#pragma unroll
        for (int r = 0; r < 4; r++)
          pk[r] = (bf16)((acc[i][j][r] + bq[b * OC + o + r]) * 0.0625f);
        *(bf16x4*)(qt + ((size_t)b * HW + p) * CH + o) = pk;
      } else if (o < 2 * CH) {  // k
        bf16x4 pk;
#pragma unroll
        for (int r = 0; r < 4; r++)
          pk[r] = (bf16)(acc[i][j][r] + bq[b * OC + o + r]);
        *(bf16x4*)(kt + ((size_t)b * HW + p) * CH + (o - CH)) = pk;
      } else {  // v, stored [c][m]
#pragma unroll
        for (int r = 0; r < 4; r++)
          vv[((size_t)b * CH + (o - 2 * CH + r)) * HW + p] =
              (bf16)(acc[i][j][r] + bq[b * OC + o + r]);
      }
    }
  }
}

// ---------------- K6: flash attention, split-m x2 ----------------
// grid (32 qtiles, 2 m-halves, 8 batches); 4 waves, wave owns 32 Q rows.
__global__ __launch_bounds__(256, 2) void attn(const bf16* __restrict__ qt,
    const bf16* __restrict__ kt, const bf16* __restrict__ vv,
    bf16* __restrict__ opart, float* __restrict__ mstat, float* __restrict__ lstat) {
  __shared__ __align__(16) bf16 Ks[32 * 256];   // [m][c]
  __shared__ __align__(16) bf16 Vs[256 * 32];   // [c][m]
  __shared__ __align__(16) bf16 Ps[4][2][512];  // per (wave,nsub): [16 n][32 m]
  int b = blockIdx.z, mh = blockIdx.y, q0 = blockIdx.x * 128;
  int tid = threadIdx.x, lane = tid & 63, w = tid >> 6;
  int l15 = lane & 15, quad = lane >> 4;
  // Q fragments (rows q0+w*32 .. +32), already scaled by 1/16
  bf16x8 qf[2][8];
  const bf16* qb = qt + ((size_t)b * HW + q0 + w * 32) * CH;
#pragma unroll
  for (int ns = 0; ns < 2; ns++)
#pragma unroll
    for (int kc = 0; kc < 8; kc++)
      qf[ns][kc] = *(const bf16x8*)(qb + (size_t)(ns * 16 + l15) * CH + kc * 32 + quad * 8);
  f32x4 zero = {0.f, 0.f, 0.f, 0.f};
  f32x4 o[2][16];
#pragma unroll
  for (int ns = 0; ns < 2; ns++)
#pragma unroll
    for (int t = 0; t < 16; t++) o[ns][t] = zero;
  float mrow[2][4], lrow[2][4];
#pragma unroll
  for (int ns = 0; ns < 2; ns++)
#pragma unroll
    for (int r = 0; r < 4; r++) { mrow[ns][r] = -1e30f; lrow[ns][r] = 0.f; }
  const bf16* kb_base = kt + (size_t)b * HW * CH;
  const bf16* vb_base = vv + (size_t)b * CH * HW;
  for (int mt = 0; mt < 64; mt++) {
    int m0 = (mh * 64 + mt) * 32;
    __syncthreads();
    const bf16* kb = kb_base + (size_t)m0 * CH;
#pragma unroll
    for (int i = 0; i < 4; i++) {  // K tile: 32 rows x 512 B
      int idx = i * 256 + tid, r = idx >> 5, ch = idx & 31;
      gl2lds16(kb + (size_t)r * CH + ch * 8, Ks + idx * 8);
    }
#pragma unroll
    for (int i = 0; i < 4; i++) {  // V tile: 256 rows x 64 B
      int idx = i * 256 + tid, c = idx >> 2, ch = idx & 3;
      gl2lds16(vb_base + (size_t)c * HW + m0 + ch * 8, Vs + idx * 8);
    }
    __syncthreads();
    // S = Q K^T  (32 n x 32 m per wave)
    f32x4 s[2][2];
#pragma unroll
    for (int ns = 0; ns < 2; ns++)
#pragma unroll
      for (int ms = 0; ms < 2; ms++) s[ns][ms] = zero;
#pragma unroll
    for (int kc = 0; kc < 8; kc++) {
      bf16x8 kf[2];
#pragma unroll
      for (int ms = 0; ms < 2; ms++)
        kf[ms] = *(const bf16x8*)(Ks + (size_t)(ms * 16 + l15) * 256 + kc * 32 + quad * 8);
#pragma unroll
      for (int ns = 0; ns < 2; ns++)
#pragma unroll
        for (int ms = 0; ms < 2; ms++) s[ns][ms] = MFMA16(qf[ns][kc], kf[ms], s[ns][ms]);
    }
    // online softmax
#pragma unroll
    for (int ns = 0; ns < 2; ns++) {
      float al[4];
#pragma unroll
      for (int r = 0; r < 4; r++) {
        float s0 = s[ns][0][r], s1 = s[ns][1][r];
        float mx = fmaxf(s0, s1);
#pragma unroll
        for (int off = 1; off < 16; off <<= 1) mx = fmaxf(mx, __shfl_xor(mx, off));
        float mnew = fmaxf(mrow[ns][r], mx);
        float alpha = __expf(mrow[ns][r] - mnew);
        float p0 = __expf(s0 - mnew), p1 = __expf(s1 - mnew);
        float rsum = p0 + p1;
#pragma unroll
        for (int off = 1; off < 16; off <<= 1) rsum += __shfl_xor(rsum, off);
        mrow[ns][r] = mnew;
        lrow[ns][r] = lrow[ns][r] * alpha + rsum;
        al[r] = alpha;
        int prow = quad * 4 + r;  // C-layout -> LDS [n][m] for A-operand reload
        Ps[w][ns][prow * 32 + l15] = (bf16)p0;
        Ps[w][ns][prow * 32 + 16 + l15] = (bf16)p1;
      }
#pragma unroll
      for (int t = 0; t < 16; t++) {
        f32x4 ov = o[ns][t];
#pragma unroll
        for (int r = 0; r < 4; r++) ov[r] *= al[r];
        o[ns][t] = ov;
      }
    }
    bf16x8 pa[2];
#pragma unroll
    for (int ns = 0; ns < 2; ns++)
      pa[ns] = *(const bf16x8*)(&Ps[w][ns][l15 * 32 + quad * 8]);
#pragma unroll
    for (int t = 0; t < 16; t++) {  // O += P V
      bf16x8 vf = *(const bf16x8*)(Vs + (size_t)(t * 16 + l15) * 32 + quad * 8);
      o[0][t] = MFMA16(pa[0], vf, o[0][t]);
      o[1][t] = MFMA16(pa[1], vf, o[1][t]);
    }
  }
  // epilogue: normalized partial O + (m,l) stats
  bf16* ob = opart + ((size_t)(mh * BATCH + b) * HW + q0 + w * 32) * CH;
#pragma unroll
  for (int ns = 0; ns < 2; ns++) {
#pragma unroll
    for (int r = 0; r < 4; r++) {
      int n = ns * 16 + quad * 4 + r;
      float inv = 1.0f / lrow[ns][r];
#pragma unroll
      for (int t = 0; t < 16; t++)
        ob[(size_t)n * CH + t * 16 + l15] = (bf16)(o[ns][t][r] * inv);
      if (l15 == 0) {
        size_t si = (size_t)(mh * BATCH + b) * HW + q0 + w * 32 + n;
        mstat[si] = mrow[ns][r];
        lstat[si] = lrow[ns][r];
      }
    }
  }
}

// ---------------- K7: combine the two m-halves ----------------
__global__ __launch_bounds__(256) void combine(const bf16* __restrict__ opart,
    const float* __restrict__ mstat, const float* __restrict__ lstat,
    bf16* __restrict__ ot) {
  int n = blockIdx.x, b = blockIdx.y, c = threadIdx.x;
  size_t i0 = (size_t)(0 * BATCH + b) * HW + n;
  size_t i1 = (size_t)(1 * BATCH + b) * HW + n;
  float m0 = mstat[i0], m1 = mstat[i1];
  float M = fmaxf(m0, m1);
  float w0 = __expf(m0 - M) * lstat[i0];
  float w1 = __expf(m1 - M) * lstat[i1];
  float inv = 1.0f / (w0 + w1);
  w0 *= inv; w1 *= inv;
  float v = w0 * (float)opart[i0 * CH + c] + w1 * (float)opart[i1 * CH + c];
  ot[((size_t)b * HW + n) * CH + c] = (bf16)v;
}

// ---------------- K8: proj GEMM + bias + residual ----------------
__global__ __launch_bounds__(256) void proj_gemm(const bf16* __restrict__ pw,
    const float* __restrict__ pbias, const bf16* __restrict__ ot,
    const float* __restrict__ x, float* __restrict__ out) {
  __shared__ __align__(16) bf16 As[128 * 32];
  __shared__ __align__(16) bf16 Bs[128 * 32];
  int b = blockIdx.z, row0 = blockIdx.y * 128, col0 = blockIdx.x * 128;
  const bf16* A = pw + (size_t)row0 * CH;
  const bf16* Bt = ot + (size_t)b * HW * CH + (size_t)col0 * CH;
  int tid = threadIdx.x, lane = tid & 63, wave = tid >> 6;
  int wm = (wave & 1) * 64, wn = (wave >> 1) * 64;
  int l15 = lane & 15, quad = lane >> 4;
  f32x4 zero = {0.f, 0.f, 0.f, 0.f};
  f32x4 acc[4][4];
#pragma unroll
  for (int i = 0; i < 4; i++)
#pragma unroll
    for (int j = 0; j < 4; j++) acc[i][j] = zero;
  for (int k0 = 0; k0 < CH; k0 += 32) {
    __syncthreads();
#pragma unroll
    for (int i = 0; i < 2; i++) {
      int idx = i * 256 + tid, r = idx >> 2, ch = idx & 3;
      gl2lds16(A + (size_t)r * CH + k0 + ch * 8, As + idx * 8);
    }
#pragma unroll
    for (int i = 0; i < 2; i++) {
      int idx = i * 256 + tid, r = idx >> 2, ch = idx & 3;
      gl2lds16(Bt + (size_t)r * CH + k0 + ch * 8, Bs + idx * 8);
    }
    __syncthreads();
    bf16x8 af[4], bfr[4];
#pragma unroll
    for (int i = 0; i < 4; i++) {
      af[i] = *(const bf16x8*)(As + (wm + i * 16 + l15) * 32 + quad * 8);
      bfr[i] = *(const bf16x8*)(Bs + (wn + i * 16 + l15) * 32 + quad * 8);
    }
#pragma unroll
    for (int i = 0; i < 4; i++)
#pragma unroll
      for (int j = 0; j < 4; j++) acc[i][j] = MFMA16(af[i], bfr[j], acc[i][j]);
  }
#pragma unroll
  for (int i = 0; i < 4; i++) {
#pragma unroll
    for (int j = 0; j < 4; j++) {
      int p = col0 + wn + j * 16 + l15;
#pragma unroll
      for (int r = 0; r < 4; r++) {
        int oo = row0 + wm + i * 16 + quad * 4 + r;
        size_t off = ((size_t)b * CH + oo) * HW + p;
        out[off] = x[off] + pbias[oo] + acc[i][j][r];
      }
    }
  }
}

extern "C" void kernel_launch(void* const* d_in, const int* in_sizes, int n_in,
                              void* d_out, int out_size, void* d_ws, size_t ws_size,
                              hipStream_t stream) {
  const float* x = (const float*)d_in[0];
  const float* nw = (const float*)d_in[1];
  const float* nb = (const float*)d_in[2];
  const float* qkvw = (const float*)d_in[3];
  const float* qkvb = (const float*)d_in[4];
  const float* projw = (const float*)d_in[5];
  const float* projb = (const float*)d_in[6];
  float* out = (float*)d_out;
  char* ws = (char*)d_ws;
  float* scale = (float*)(ws + 0);           // 8 KB
  float* shift = (float*)(ws + 8192);        // 8 KB
  float* bq    = (float*)(ws + 16384);       // 24 KB
  bf16* pwb    = (bf16*)(ws + 40960);        // 128 KB
  bf16* wq     = (bf16*)(ws + 172032);       // 3 MB
  bf16* xt     = (bf16*)(ws + 3317760);      // 16 MB (aliased with ot)
  bf16* qt     = (bf16*)(ws + 20094976);     // 16 MB
  bf16* kt     = (bf16*)(ws + 36872192);     // 16 MB
  bf16* vv     = (bf16*)(ws + 53649408);     // 16 MB
  bf16* opart  = (bf16*)(ws + 70426624);     // 32 MB
  float* mstat = (float*)(ws + 103981056);   // 256 KB
  float* lstat = (float*)(ws + 104243200);   // 256 KB  -> total ~100 MB
  bf16* ot = xt;  // xt dead after qkv_gemm

  gn_stats<<<64, 1024, 0, stream>>>(x, nw, nb, scale, shift);
  fold_qkv<<<dim3(768, 8), 256, 0, stream>>>(qkvw, qkvb, scale, shift, wq, bq);
  transpose_x<<<dim3(128, 8, 8), dim3(32, 8), 0, stream>>>(x, xt);
  conv_projw<<<256, 256, 0, stream>>>(projw, pwb);
  qkv_gemm<<<dim3(32, 6, 8), 256, 0, stream>>>(wq, bq, xt, qt, kt, vv);
  attn<<<dim3(32, 2, 8), 256, 0, stream>>>(qt, kt, vv, opart, mstat, lstat);
  combine<<<dim3(4096, 8), 256, 0, stream>>>(opart, mstat, lstat, ot);
  proj_gemm<<<dim3(32, 2, 8), 256, 0, stream>>>(pwb, projb, ot, x, out);
}

// Round 3
// 373.249 us; speedup vs baseline: 1.4330x; 1.4330x over previous
//
#include <hip/hip_runtime.h>
#include <stdint.h>

#define BATCH 8
#define CH 256
#define HW 4096
#define OC 768  // 3*CH

typedef __bf16 bf16;
typedef __attribute__((ext_vector_type(8))) __bf16 bf16x8;
typedef __attribute__((ext_vector_type(4))) __bf16 bf16x4;
typedef __attribute__((ext_vector_type(2))) __bf16 bf16x2;
typedef __attribute__((ext_vector_type(4))) float f32x4;
typedef __attribute__((ext_vector_type(4))) int i32x4;

#define MFMA16(a, b, c) __builtin_amdgcn_mfma_f32_16x16x32_bf16(a, b, c, 0, 0, 0)

static __device__ __forceinline__ void gl2lds16(const void* g, void* l) {
  __builtin_amdgcn_global_load_lds((const __attribute__((address_space(1))) void*)g,
                                   (__attribute__((address_space(3))) void*)l, 16, 0, 0);
}

static __device__ __forceinline__ int packbf(float a, float b) {
  bf16x2 v;
  v[0] = (bf16)a;
  v[1] = (bf16)b;
  return __builtin_bit_cast(int, v);
}

// ---------- K1: fused transpose (x[b][c][p] fp32 -> xt[b][p][c] bf16) + GN partial stats ----------
__global__ __launch_bounds__(256) void trans_stats(const float* __restrict__ x,
    bf16* __restrict__ xt, float* __restrict__ partial) {
  __shared__ float tile[32][33];
  __shared__ float red[8];
  int b = blockIdx.z, ct = blockIdx.y, pt = blockIdx.x;
  int p0 = pt * 32, c0 = ct * 32;
  const float* xb = x + (size_t)b * CH * HW;
  float s = 0.f, s2 = 0.f;
#pragma unroll
  for (int i = 0; i < 4; i++) {
    int c = c0 + threadIdx.y + i * 8;
    float v = xb[(size_t)c * HW + p0 + threadIdx.x];
    tile[threadIdx.y + i * 8][threadIdx.x] = v;
    s += v;
    s2 += v * v;
  }
  int tid = threadIdx.y * 32 + threadIdx.x;
  for (int off = 32; off; off >>= 1) { s += __shfl_down(s, off); s2 += __shfl_down(s2, off); }
  if ((tid & 63) == 0) { red[(tid >> 6) * 2] = s; red[(tid >> 6) * 2 + 1] = s2; }
  __syncthreads();
  if (tid == 0) {
    float* pp = partial + ((size_t)(b * 8 + ct) * 128 + pt) * 2;
    pp[0] = red[0] + red[2] + red[4] + red[6];
    pp[1] = red[1] + red[3] + red[5] + red[7];
  }
  bf16* xtb = xt + (size_t)b * HW * CH;
#pragma unroll
  for (int i = 0; i < 4; i++) {
    int p = p0 + threadIdx.y + i * 8;
    xtb[(size_t)p * CH + c0 + threadIdx.x] = (bf16)tile[threadIdx.x][threadIdx.y + i * 8];
  }
}

// ---------- K2: finalize GN stats -> per-(b,c) scale/shift ----------
__global__ __launch_bounds__(128) void gn_finalize(const float* __restrict__ partial,
    const float* __restrict__ nw, const float* __restrict__ nb,
    float* __restrict__ scale, float* __restrict__ shift) {
  int bg = blockIdx.x;  // b*8+g
  int t = threadIdx.x;  // 128
  const float* pp = partial + (size_t)bg * 128 * 2;
  float s = pp[t * 2], s2 = pp[t * 2 + 1];
  __shared__ float red[4], mm[2];
  for (int off = 32; off; off >>= 1) { s += __shfl_down(s, off); s2 += __shfl_down(s2, off); }
  if ((t & 63) == 0) { red[(t >> 6) * 2] = s; red[(t >> 6) * 2 + 1] = s2; }
  __syncthreads();
  if (t == 0) {
    float ts = red[0] + red[2], ts2 = red[1] + red[3];
    float mean = ts * (1.0f / 131072.0f);
    float var = ts2 * (1.0f / 131072.0f) - mean * mean;
    mm[0] = mean;
    mm[1] = rsqrtf(var + 1e-5f);
  }
  __syncthreads();
  if (t < 32) {
    int b = bg >> 3, g = bg & 7, c = g * 32 + t;
    float sc = nw[c] * mm[1];
    scale[b * CH + c] = sc;
    shift[b * CH + c] = nb[c] - mm[0] * sc;
  }
}

// ---------- K3: fold GN into per-batch QKV weights (bf16) ----------
__global__ __launch_bounds__(256) void fold_qkv(const float* __restrict__ qkv_w,
    const float* __restrict__ qkv_b, const float* __restrict__ scale,
    const float* __restrict__ shift, bf16* __restrict__ wq, float* __restrict__ bq) {
  int o = blockIdx.x, b = blockIdx.y, c = threadIdx.x;
  float w = qkv_w[o * CH + c];
  wq[((size_t)b * OC + o) * CH + c] = (bf16)(w * scale[b * CH + c]);
  float part = w * shift[b * CH + c];
  __shared__ float red[4];
  for (int off = 32; off; off >>= 1) part += __shfl_down(part, off);
  if ((threadIdx.x & 63) == 0) red[threadIdx.x >> 6] = part;
  __syncthreads();
  if (threadIdx.x == 0) bq[b * OC + o] = qkv_b[o] + red[0] + red[1] + red[2] + red[3];
}

// ---------- K4: proj_w -> bf16 ----------
__global__ __launch_bounds__(256) void conv_projw(const float* __restrict__ w,
                                                  bf16* __restrict__ wb) {
  int i = blockIdx.x * 256 + threadIdx.x;
  wb[i] = (bf16)w[i];
}

// ---------- K5: QKV GEMM (128x128 tile, BK=32, global_load_lds) ----------
__global__ __launch_bounds__(256) void qkv_gemm(const bf16* __restrict__ wq,
    const float* __restrict__ bq, const bf16* __restrict__ xt,
    bf16* __restrict__ qt, bf16* __restrict__ kt, bf16* __restrict__ vv) {
  __shared__ __align__(16) bf16 As[128 * 32];
  __shared__ __align__(16) bf16 Bs[128 * 32];
  int b = blockIdx.z, row0 = blockIdx.y * 128, col0 = blockIdx.x * 128;
  const bf16* A = wq + (size_t)b * OC * CH + (size_t)row0 * CH;
  const bf16* Bt = xt + (size_t)b * HW * CH + (size_t)col0 * CH;
  int tid = threadIdx.x, lane = tid & 63, wave = tid >> 6;
  int wm = (wave & 1) * 64, wn = (wave >> 1) * 64;
  int l15 = lane & 15, quad = lane >> 4;
  f32x4 zero = {0.f, 0.f, 0.f, 0.f};
  f32x4 acc[4][4];
#pragma unroll
  for (int i = 0; i < 4; i++)
#pragma unroll
    for (int j = 0; j < 4; j++) acc[i][j] = zero;
  for (int k0 = 0; k0 < CH; k0 += 32) {
    __syncthreads();
#pragma unroll
    for (int i = 0; i < 2; i++) {
      int idx = i * 256 + tid, r = idx >> 2, ch = idx & 3;
      gl2lds16(A + (size_t)r * CH + k0 + ch * 8, As + idx * 8);
    }
#pragma unroll
    for (int i = 0; i < 2; i++) {
      int idx = i * 256 + tid, r = idx >> 2, ch = idx & 3;
      gl2lds16(Bt + (size_t)r * CH + k0 + ch * 8, Bs + idx * 8);
    }
    __syncthreads();
    bf16x8 af[4], bfr[4];
#pragma unroll
    for (int i = 0; i < 4; i++) {
      af[i] = *(const bf16x8*)(As + (wm + i * 16 + l15) * 32 + quad * 8);
      bfr[i] = *(const bf16x8*)(Bs + (wn + i * 16 + l15) * 32 + quad * 8);
    }
#pragma unroll
    for (int i = 0; i < 4; i++)
#pragma unroll
      for (int j = 0; j < 4; j++) acc[i][j] = MFMA16(af[i], bfr[j], acc[i][j]);
  }
#pragma unroll
  for (int i = 0; i < 4; i++) {
    int o = row0 + wm + i * 16 + quad * 4;  // + r
#pragma unroll
    for (int j = 0; j < 4; j++) {
      int p = col0 + wn + j * 16 + l15;
      if (o < CH) {  // q, fold 1/sqrt(C)=1/16
        bf16x4 pk;
#pragma unroll
        for (int r = 0; r < 4; r++)
          pk[r] = (bf16)((acc[i][j][r] + bq[b * OC + o + r]) * 0.0625f);
        *(bf16x4*)(qt + ((size_t)b * HW + p) * CH + o) = pk;
      } else if (o < 2 * CH) {  // k
        bf16x4 pk;
#pragma unroll
        for (int r = 0; r < 4; r++)
          pk[r] = (bf16)(acc[i][j][r] + bq[b * OC + o + r]);
        *(bf16x4*)(kt + ((size_t)b * HW + p) * CH + (o - CH)) = pk;
      } else {  // v, stored [c][m]
#pragma unroll
        for (int r = 0; r < 4; r++)
          vv[((size_t)b * CH + (o - 2 * CH + r)) * HW + p] =
              (bf16)(acc[i][j][r] + bq[b * OC + o + r]);
      }
    }
  }
}

// ---------- K6: flash attention (S^T form), split-m x2 ----------
// S^T = K·Q^T so each lane's softmax row is n = lane&15: row reductions are 2
// shuffles; alpha / 1/l apply per-lane with no broadcast. P reaches the PV
// MFMA B-operand via 16 ds_bpermute (no LDS round-trip). Ks/Vs are XOR-group
// swizzled at stage time -> 2-way (free) bank access on fragment reads.
__global__ __launch_bounds__(256, 2) void attn(const bf16* __restrict__ qt,
    const bf16* __restrict__ kt, const bf16* __restrict__ vv,
    bf16* __restrict__ opart, float* __restrict__ mstat, float* __restrict__ lstat) {
  __shared__ __align__(16) bf16 Ks[32 * 256];  // [m][c], 16B-group g stored at g^(m&7)
  __shared__ __align__(16) bf16 Vs[256 * 32];  // [c][m], 16B-group g stored at g^((c>>1)&3)
  int b = blockIdx.z, mh = blockIdx.y, q0 = blockIdx.x * 128;
  int tid = threadIdx.x, lane = tid & 63, w = tid >> 6;
  int l15 = lane & 15, quad = lane >> 4;
  bf16x8 qf[2][8];
  const bf16* qb = qt + ((size_t)b * HW + q0 + w * 32) * CH;
#pragma unroll
  for (int ns = 0; ns < 2; ns++)
#pragma unroll
    for (int kc = 0; kc < 8; kc++)
      qf[ns][kc] = *(const bf16x8*)(qb + (size_t)(ns * 16 + l15) * CH + kc * 32 + quad * 8);
  f32x4 zero = {0.f, 0.f, 0.f, 0.f};
  f32x4 o[2][16];
#pragma unroll
  for (int ns = 0; ns < 2; ns++)
#pragma unroll
    for (int t = 0; t < 16; t++) o[ns][t] = zero;
  float mrow[2] = {-1e30f, -1e30f}, lrow[2] = {0.f, 0.f};
  const bf16* kb_base = kt + (size_t)b * HW * CH;
  const bf16* vb_base = vv + (size_t)b * CH * HW;
  int kswz = l15 & 7;
  int vswz = (l15 >> 1) & 3;
  for (int mt = 0; mt < 64; mt++) {
    int m0 = (mh * 64 + mt) * 32;
    __syncthreads();
    const bf16* kb = kb_base + (size_t)m0 * CH;
#pragma unroll
    for (int i = 0; i < 4; i++) {
      int idx = i * 256 + tid, r = idx >> 5, pg = idx & 31;
      gl2lds16(kb + (size_t)r * CH + (pg ^ (r & 7)) * 8, Ks + idx * 8);
    }
#pragma unroll
    for (int i = 0; i < 4; i++) {
      int idx = i * 256 + tid, c = idx >> 2, pg = idx & 3;
      gl2lds16(vb_base + (size_t)c * HW + m0 + (pg ^ ((c >> 1) & 3)) * 8, Vs + idx * 8);
    }
    __syncthreads();
    f32x4 s[2][2];  // [ms][ns]; lane holds S[n=l15][m = ms*16+quad*4+r]
#pragma unroll
    for (int ms = 0; ms < 2; ms++)
#pragma unroll
      for (int ns = 0; ns < 2; ns++) s[ms][ns] = zero;
#pragma unroll
    for (int kc = 0; kc < 8; kc++) {
      bf16x8 kf[2];
#pragma unroll
      for (int ms = 0; ms < 2; ms++)
        kf[ms] = *(const bf16x8*)(Ks + (size_t)(ms * 16 + l15) * 256 + ((kc * 4 + quad) ^ kswz) * 8);
#pragma unroll
      for (int ms = 0; ms < 2; ms++)
#pragma unroll
        for (int ns = 0; ns < 2; ns++) s[ms][ns] = MFMA16(kf[ms], qf[ns][kc], s[ms][ns]);
    }
    bf16x8 pa[2];
#pragma unroll
    for (int ns = 0; ns < 2; ns++) {
      float mx = s[0][ns][0];
#pragma unroll
      for (int r = 1; r < 4; r++) mx = fmaxf(mx, s[0][ns][r]);
#pragma unroll
      for (int r = 0; r < 4; r++) mx = fmaxf(mx, s[1][ns][r]);
      mx = fmaxf(mx, __shfl_xor(mx, 16));
      mx = fmaxf(mx, __shfl_xor(mx, 32));
      float mnew = fmaxf(mrow[ns], mx);
      float alpha = __expf(mrow[ns] - mnew);
      float p0[4], p1[4], sum = 0.f;
#pragma unroll
      for (int r = 0; r < 4; r++) { p0[r] = __expf(s[0][ns][r] - mnew); sum += p0[r]; }
#pragma unroll
      for (int r = 0; r < 4; r++) { p1[r] = __expf(s[1][ns][r] - mnew); sum += p1[r]; }
      sum += __shfl_xor(sum, 16);
      sum += __shfl_xor(sum, 32);
      mrow[ns] = mnew;
      lrow[ns] = lrow[ns] * alpha + sum;
      // transpose P (C-layout) -> B-frag of P^T via bpermute
      int pk0[2] = {packbf(p0[0], p0[1]), packbf(p0[2], p0[3])};
      int pk1[2] = {packbf(p1[0], p1[1]), packbf(p1[2], p1[3])};
      i32x4 pr;
#pragma unroll
      for (int v = 0; v < 4; v++) {
        int srcLane = (((quad & 1) << 1) + (v >> 1)) * 16 + l15;
        int a0 = __builtin_amdgcn_ds_bpermute(srcLane << 2, pk0[v & 1]);
        int a1 = __builtin_amdgcn_ds_bpermute(srcLane << 2, pk1[v & 1]);
        pr[v] = (quad >> 1) ? a1 : a0;
      }
      pa[ns] = __builtin_bit_cast(bf16x8, pr);
#pragma unroll
      for (int t = 0; t < 16; t++) {
#pragma unroll
        for (int r = 0; r < 4; r++) o[ns][t][r] *= alpha;
      }
    }
#pragma unroll
    for (int t = 0; t < 16; t++) {  // O^T = V^T · P^T
      bf16x8 vf = *(const bf16x8*)(Vs + (size_t)(t * 16 + l15) * 32 + (quad ^ vswz) * 8);
      o[0][t] = MFMA16(vf, pa[0], o[0][t]);
      o[1][t] = MFMA16(vf, pa[1], o[1][t]);
    }
  }
  // epilogue: normalized partial O^T -> opart[mh][b][c][p], coalesced over l15
  int ncol = q0 + w * 32 + l15;
#pragma unroll
  for (int ns = 0; ns < 2; ns++) {
    float inv = 1.0f / lrow[ns];
    bf16* ob = opart + (size_t)(mh * BATCH + b) * CH * HW + ncol + ns * 16;
#pragma unroll
    for (int t = 0; t < 16; t++)
#pragma unroll
      for (int r = 0; r < 4; r++)
        ob[(size_t)(t * 16 + quad * 4 + r) * HW] = (bf16)(o[ns][t][r] * inv);
    if (quad == 0) {
      size_t si = (size_t)(mh * BATCH + b) * HW + ncol + ns * 16;
      mstat[si] = mrow[ns];
      lstat[si] = lrow[ns];
    }
  }
}

// ---------- K7: combine two m-halves + transpose [c][p] -> ot[p][c] ----------
__global__ __launch_bounds__(256) void combine_t(const bf16* __restrict__ opart,
    const float* __restrict__ mstat, const float* __restrict__ lstat,
    bf16* __restrict__ ot) {
  __shared__ float tile[32][33];
  int b = blockIdx.z, p0 = blockIdx.x * 32, c0 = blockIdx.y * 32;
  int tx = threadIdx.x, ty = threadIdx.y;
  int p = p0 + tx;
  size_t s0 = (size_t)(0 * BATCH + b) * HW + p;
  size_t s1 = (size_t)(1 * BATCH + b) * HW + p;
  float m0 = mstat[s0], m1 = mstat[s1];
  float M = fmaxf(m0, m1);
  float w0 = __expf(m0 - M) * lstat[s0];
  float w1 = __expf(m1 - M) * lstat[s1];
  float inv = 1.0f / (w0 + w1);
  w0 *= inv;
  w1 *= inv;
#pragma unroll
  for (int i = 0; i < 4; i++) {
    int c = c0 + ty + i * 8;
    tile[ty + i * 8][tx] =
        w0 * (float)opart[((size_t)(0 * BATCH + b) * CH + c) * HW + p] +
        w1 * (float)opart[((size_t)(1 * BATCH + b) * CH + c) * HW + p];
  }
  __syncthreads();
#pragma unroll
  for (int i = 0; i < 4; i++) {
    int pp = p0 + ty + i * 8;
    ot[((size_t)b * HW + pp) * CH + c0 + tx] = (bf16)tile[tx][ty + i * 8];
  }
}

// ---------- K8: proj GEMM + bias + residual ----------
__global__ __launch_bounds__(256) void proj_gemm(const bf16* __restrict__ pw,
    const float* __restrict__ pbias, const bf16* __restrict__ ot,
    const float* __restrict__ x, float* __restrict__ out) {
  __shared__ __align__(16) bf16 As[128 * 32];
  __shared__ __align__(16) bf16 Bs[128 * 32];
  int b = blockIdx.z, row0 = blockIdx.y * 128, col0 = blockIdx.x * 128;
  const bf16* A = pw + (size_t)row0 * CH;
  const bf16* Bt = ot + (size_t)b * HW * CH + (size_t)col0 * CH;
  int tid = threadIdx.x, lane = tid & 63, wave = tid >> 6;
  int wm = (wave & 1) * 64, wn = (wave >> 1) * 64;
  int l15 = lane & 15, quad = lane >> 4;
  f32x4 zero = {0.f, 0.f, 0.f, 0.f};
  f32x4 acc[4][4];
#pragma unroll
  for (int i = 0; i < 4; i++)
#pragma unroll
    for (int j = 0; j < 4; j++) acc[i][j] = zero;
  for (int k0 = 0; k0 < CH; k0 += 32) {
    __syncthreads();
#pragma unroll
    for (int i = 0; i < 2; i++) {
      int idx = i * 256 + tid, r = idx >> 2, ch = idx & 3;
      gl2lds16(A + (size_t)r * CH + k0 + ch * 8, As + idx * 8);
    }
#pragma unroll
    for (int i = 0; i < 2; i++) {
      int idx = i * 256 + tid, r = idx >> 2, ch = idx & 3;
      gl2lds16(Bt + (size_t)r * CH + k0 + ch * 8, Bs + idx * 8);
    }
    __syncthreads();
    bf16x8 af[4], bfr[4];
#pragma unroll
    for (int i = 0; i < 4; i++) {
      af[i] = *(const bf16x8*)(As + (wm + i * 16 + l15) * 32 + quad * 8);
      bfr[i] = *(const bf16x8*)(Bs + (wn + i * 16 + l15) * 32 + quad * 8);
    }
#pragma unroll
    for (int i = 0; i < 4; i++)
#pragma unroll
      for (int j = 0; j < 4; j++) acc[i][j] = MFMA16(af[i], bfr[j], acc[i][j]);
  }
#pragma unroll
  for (int i = 0; i < 4; i++) {
#pragma unroll
    for (int j = 0; j < 4; j++) {
      int p = col0 + wn + j * 16 + l15;
#pragma unroll
      for (int r = 0; r < 4; r++) {
        int oo = row0 + wm + i * 16 + quad * 4 + r;
        size_t off = ((size_t)b * CH + oo) * HW + p;
        out[off] = x[off] + pbias[oo] + acc[i][j][r];
      }
    }
  }
}

extern "C" void kernel_launch(void* const* d_in, const int* in_sizes, int n_in,
                              void* d_out, int out_size, void* d_ws, size_t ws_size,
                              hipStream_t stream) {
  const float* x = (const float*)d_in[0];
  const float* nw = (const float*)d_in[1];
  const float* nb = (const float*)d_in[2];
  const float* qkvw = (const float*)d_in[3];
  const float* qkvb = (const float*)d_in[4];
  const float* projw = (const float*)d_in[5];
  const float* projb = (const float*)d_in[6];
  float* out = (float*)d_out;
  char* ws = (char*)d_ws;
  float* scale = (float*)(ws + 0);           // 8 KB
  float* shift = (float*)(ws + 8192);        // 8 KB
  float* bq    = (float*)(ws + 16384);       // 24 KB
  bf16* pwb    = (bf16*)(ws + 40960);        // 128 KB
  bf16* wq     = (bf16*)(ws + 172032);       // 3 MB
  bf16* xt     = (bf16*)(ws + 3317760);      // 16 MB (aliased with ot)
  bf16* qt     = (bf16*)(ws + 20094976);     // 16 MB
  bf16* kt     = (bf16*)(ws + 36872192);     // 16 MB
  bf16* vv     = (bf16*)(ws + 53649408);     // 16 MB
  bf16* opart  = (bf16*)(ws + 70426624);     // 32 MB
  float* mstat = (float*)(ws + 103981056);   // 256 KB
  float* lstat = (float*)(ws + 104243200);   // 256 KB
  float* partial = (float*)(ws + 70426624);  // 64 KB, aliases opart (dead before attn)
  bf16* ot = xt;  // xt dead after qkv_gemm

  trans_stats<<<dim3(128, 8, 8), dim3(32, 8), 0, stream>>>(x, xt, partial);
  gn_finalize<<<64, 128, 0, stream>>>(partial, nw, nb, scale, shift);
  fold_qkv<<<dim3(768, 8), 256, 0, stream>>>(qkvw, qkvb, scale, shift, wq, bq);
  conv_projw<<<256, 256, 0, stream>>>(projw, pwb);
  qkv_gemm<<<dim3(32, 6, 8), 256, 0, stream>>>(wq, bq, xt, qt, kt, vv);
  attn<<<dim3(32, 2, 8), 256, 0, stream>>>(qt, kt, vv, opart, mstat, lstat);
  combine_t<<<dim3(128, 8, 8), dim3(32, 8), 0, stream>>>(opart, mstat, lstat, ot);
  proj_gemm<<<dim3(32, 2, 8), 256, 0, stream>>>(pwb, projb, ot, x, out);
}